// Round 2
// baseline (147.916 us; speedup 1.0000x reference)
//
#include <hip/hip_runtime.h>
#include <cstdint>
#include <cstddef>

// Problem constants (from reference setup_inputs / module constants)
#define RB  2
#define RC  256
#define RH  100
#define RW  152
#define RHW (RH * RW)      // 15200
#define RPH 7
#define RPW 7
#define RNB (RPH * RPW)    // 49 bins per ROI
#define HWT 475            // RHW / 32 (exact)
#define CT  8              // RC / 32
constexpr float kScale = 0.0625f;

// ---------------------------------------------------------------------------
// Kernel 1: NCHW -> NHWC transpose (per batch: [C][HW] -> [HW][C]).
// 1-D grid; tiled 32x32 via LDS; both global sides coalesced; scalar dwords.
// ---------------------------------------------------------------------------
__global__ __launch_bounds__(256) void transpose_nchw_nhwc(
    const float* __restrict__ in, float* __restrict__ out) {
  __shared__ float tile[32][33];  // +1 pad: conflict-free transpose
  int bid = blockIdx.x;           // 0 .. RB*CT*HWT-1
  const int b   = bid / (CT * HWT);
  bid -= b * (CT * HWT);
  const int c0  = (bid / HWT) * 32;
  const int hw0 = (bid - (bid / HWT) * HWT) * 32;
  const int tx  = threadIdx.x & 31;   // 0..31
  const int ty  = threadIdx.x >> 5;   // 0..7
  const float* inb  = in  + (size_t)b * RC  * RHW;
  float*       outb = out + (size_t)b * RHW * RC;

#pragma unroll
  for (int j = 0; j < 32; j += 8)
    tile[ty + j][tx] = inb[(size_t)(c0 + ty + j) * RHW + (hw0 + tx)];
  __syncthreads();
#pragma unroll
  for (int j = 0; j < 32; j += 8)
    outb[(size_t)(hw0 + ty + j) * RC + (c0 + tx)] = tile[tx][ty + j];
}

// ---------------------------------------------------------------------------
// Kernel 2: RoIAlign on NHWC features.
// One block (256 threads) per ROI. Lane (cg = t&63) owns channels 4cg..4cg+3
// (one float4 per corner load: 64 lanes x 16B = the full 1KB channel vector
// at one (b,y,x), perfectly coalesced). Wave (t>>6) strides over the 49 bins
// so all coordinate math / validity branches are wave-uniform.
// Results staged in LDS in exact output order -> dword-coalesced epilogue.
// ---------------------------------------------------------------------------
__global__ __launch_bounds__(256) void roi_align_nhwc(
    const float* __restrict__ feat,   // [B][H][W][C]
    const float* __restrict__ rois,   // [R][5]
    float* __restrict__ out) {        // [R][C][7][7]
  __shared__ float lds[RC * RNB];     // 50176 B, laid out as out[c][bi]

  const int r  = blockIdx.x;
  const int t  = threadIdx.x;
  const int cg = t & 63;   // channel group: channels 4cg..4cg+3
  const int wg = t >> 6;   // wave id 0..3

  const float* roi = rois + (size_t)r * 5;
  int b = (int)roi[0];
  b = (b < 0) ? 0 : (b >= RB ? RB - 1 : b);
  const float sw    = roi[1] * kScale;
  const float sh    = roi[2] * kScale;
  const float ew    = roi[3] * kScale;
  const float eh    = roi[4] * kScale;
  const float roi_w = fmaxf(ew - sw, 1.0f);
  const float roi_h = fmaxf(eh - sh, 1.0f);
  const float bin_w = roi_w / 7.0f;
  const float bin_h = roi_h / 7.0f;

  const float4* fb = (const float4*)(feat + (size_t)b * RHW * RC);

  for (int bi = wg; bi < RNB; bi += 4) {
    const int ph = bi / RPW;
    const int pw = bi - ph * RPW;

    float ax = 0.f, ay = 0.f, az = 0.f, aw = 0.f;
#pragma unroll
    for (int s = 0; s < 4; ++s) {
      const int iy = s >> 1;
      const int ix = s & 1;
      // sample coord: start + (bin + (i+0.5)/SR) * bin_size, SR=2
      const float y = sh + ((float)ph + (iy ? 0.75f : 0.25f)) * bin_h;
      const float x = sw + ((float)pw + (ix ? 0.75f : 0.25f)) * bin_w;
      // validity (wave-uniform branch: y,x independent of lane)
      if (y < -1.0f || y > (float)RH || x < -1.0f || x > (float)RW) continue;

      const float yc = fminf(fmaxf(y, 0.0f), (float)(RH - 1));
      const float xc = fminf(fmaxf(x, 0.0f), (float)(RW - 1));
      const int y0 = (int)yc;             // yc >= 0, trunc == floor
      const int x0 = (int)xc;
      const int y1 = (y0 + 1 < RH) ? y0 + 1 : RH - 1;
      const int x1 = (x0 + 1 < RW) ? x0 + 1 : RW - 1;
      const float ly = yc - (float)y0;
      const float lx = xc - (float)x0;
      const float hy = 1.0f - ly;
      const float hx = 1.0f - lx;
      const float w11 = hy * hx, w12 = hy * lx, w21 = ly * hx, w22 = ly * lx;

      const float4 v11 = fb[(size_t)(y0 * RW + x0) * 64 + cg];
      const float4 v12 = fb[(size_t)(y0 * RW + x1) * 64 + cg];
      const float4 v21 = fb[(size_t)(y1 * RW + x0) * 64 + cg];
      const float4 v22 = fb[(size_t)(y1 * RW + x1) * 64 + cg];

      ax += w11 * v11.x + w12 * v12.x + w21 * v21.x + w22 * v22.x;
      ay += w11 * v11.y + w12 * v12.y + w21 * v21.y + w22 * v22.y;
      az += w11 * v11.z + w12 * v12.z + w21 * v21.z + w22 * v22.z;
      aw += w11 * v11.w + w12 * v12.w + w21 * v21.w + w22 * v22.w;
    }

    // stage in output order: lds[c*49 + bi], c = 4cg..4cg+3
    const int cbase = (cg * 4) * RNB + bi;
    lds[cbase + 0 * RNB] = ax * 0.25f;
    lds[cbase + 1 * RNB] = ay * 0.25f;
    lds[cbase + 2 * RNB] = az * 0.25f;
    lds[cbase + 3 * RNB] = aw * 0.25f;
  }

  __syncthreads();

  // Epilogue: 12544 floats, dword-coalesced (49 iters of 256 lanes).
  float* outr = out + (size_t)r * (RC * RNB);
  for (int i = t; i < RC * RNB; i += 256)
    outr[i] = lds[i];
}

// ---------------------------------------------------------------------------
// Fallback: direct NCHW gather (workspace too small or misaligned pointers).
// Correct but slow (strided channel loads, strided stores).
// ---------------------------------------------------------------------------
__global__ __launch_bounds__(256) void roi_align_nchw(
    const float* __restrict__ feat,   // [B][C][H][W]
    const float* __restrict__ rois,
    float* __restrict__ out) {
  const int r = blockIdx.x;
  const int c = threadIdx.x;

  const float* roi = rois + (size_t)r * 5;
  int b = (int)roi[0];
  b = (b < 0) ? 0 : (b >= RB ? RB - 1 : b);
  const float sw    = roi[1] * kScale;
  const float sh    = roi[2] * kScale;
  const float ew    = roi[3] * kScale;
  const float eh    = roi[4] * kScale;
  const float roi_w = fmaxf(ew - sw, 1.0f);
  const float roi_h = fmaxf(eh - sh, 1.0f);
  const float bin_w = roi_w / 7.0f;
  const float bin_h = roi_h / 7.0f;

  const float* fb = feat + ((size_t)b * RC + c) * RHW;

  for (int bi = 0; bi < RNB; ++bi) {
    const int ph = bi / RPW;
    const int pw = bi - ph * RPW;
    float acc = 0.f;
#pragma unroll
    for (int s = 0; s < 4; ++s) {
      const int iy = s >> 1;
      const int ix = s & 1;
      const float y = sh + ((float)ph + (iy ? 0.75f : 0.25f)) * bin_h;
      const float x = sw + ((float)pw + (ix ? 0.75f : 0.25f)) * bin_w;
      if (y < -1.0f || y > (float)RH || x < -1.0f || x > (float)RW) continue;

      const float yc = fminf(fmaxf(y, 0.0f), (float)(RH - 1));
      const float xc = fminf(fmaxf(x, 0.0f), (float)(RW - 1));
      const int y0 = (int)yc;
      const int x0 = (int)xc;
      const int y1 = (y0 + 1 < RH) ? y0 + 1 : RH - 1;
      const int x1 = (x0 + 1 < RW) ? x0 + 1 : RW - 1;
      const float ly = yc - (float)y0;
      const float lx = xc - (float)x0;
      const float hy = 1.0f - ly;
      const float hx = 1.0f - lx;

      acc += (hy * hx) * fb[y0 * RW + x0] + (hy * lx) * fb[y0 * RW + x1] +
             (ly * hx) * fb[y1 * RW + x0] + (ly * lx) * fb[y1 * RW + x1];
    }
    out[((size_t)r * RC + c) * RNB + bi] = acc * 0.25f;
  }
}

// ---------------------------------------------------------------------------
extern "C" void kernel_launch(void* const* d_in, const int* in_sizes, int n_in,
                              void* d_out, int out_size, void* d_ws, size_t ws_size,
                              hipStream_t stream) {
  const float* feat = (const float*)d_in[0];
  const float* rois = (const float*)d_in[1];
  float* out = (float*)d_out;
  const int R = in_sizes[1] / 5;

  const size_t need = (size_t)RB * RC * RHW * sizeof(float);  // 31.1 MB
  const bool aligned16 =
      (((uintptr_t)d_ws | (uintptr_t)d_in[0] | (uintptr_t)d_out) & 15) == 0;

  if (ws_size >= need && aligned16 && d_ws != nullptr) {
    float* nhwc = (float*)d_ws;
    transpose_nchw_nhwc<<<RB * CT * HWT, 256, 0, stream>>>(feat, nhwc);
    roi_align_nhwc<<<R, 256, 0, stream>>>(nhwc, rois, out);
  } else {
    roi_align_nchw<<<R, 256, 0, stream>>>(feat, rois, out);
  }
}